// Round 1
// 258.229 us; speedup vs baseline: 1.2698x; 1.2698x over previous
//
#include <hip/hip_runtime.h>

// RecurrentGCN (DCRNN cell, K=1) — MFMA version.
// Per previous rounds: edge_index/edge_weight are mathematically unused; the op
// is three small GEMMs ([N,48]@[48,64] z|r, [N,48]@[48,32] candidate,
// [N,32]@[32,8] out) + GRU glue. Previous kernel was LDS-issue-bound
// (1216 ds_read_b128/thread re-streaming weights per node ~= 185us).
// Here weights live in per-wave MFMA B-fragments (52 VGPR), reused across all
// node tiles; each wave owns a 16-node tile, wave-private LDS, no in-loop
// __syncthreads. Dtype-adaptive (f32 or bf16 storage) as before.

#define N_NODES 500000
#define IN_DIM  16
#define HID     32
#define OUT_DIM 8
#define XH      48         // IN_DIM + HID
#define NTILES  31250      // N_NODES / 16 (exact)

typedef unsigned int u32;
typedef unsigned short u16;
typedef __attribute__((ext_vector_type(8))) short bf16x8;  // 8 bf16 = 4 VGPR
typedef __attribute__((ext_vector_type(4))) float f32x4;   // MFMA 16x16 acc

static __device__ __forceinline__ float bfbits(u32 hi){ union{u32 x; float f;} t; t.x=hi; return t.f; }
static __device__ __forceinline__ float bflo(u32 u){ return bfbits(u<<16); }
static __device__ __forceinline__ float bfhi(u32 u){ return bfbits(u & 0xffff0000u); }
static __device__ __forceinline__ float bf2f(u16 s){ return bfbits(((u32)s)<<16); }
static __device__ __forceinline__ u16 f2bf(float f){
    union{float f;u32 x;} t; t.f=f; u32 x=t.x;
    return (u16)((x + 0x7fffu + ((x>>16)&1u)) >> 16);      // RNE
}
static __device__ __forceinline__ u32 pk2(float a, float b){
    return (u32)f2bf(a) | ((u32)f2bf(b)<<16);
}
static __device__ __forceinline__ float sigm(float a){
    a = fminf(fmaxf(a,-30.f),30.f); return 1.f/(1.f+__expf(-a));
}
static __device__ __forceinline__ float tanh_(float a){
    a = fminf(fmaxf(a,-20.f),20.f); float e = __expf(-2.f*a); return (1.f-e)/(1.f+e);
}

// wave-private LDS write->read fence (drain our own ds ops; no cross-wave dep)
#define LFENCE() asm volatile("s_waitcnt lgkmcnt(0)" ::: "memory")
#define MFMA16(a,b,c) __builtin_amdgcn_mfma_f32_16x16x32_bf16(a,b,c,0,0,0)

static __device__ __forceinline__ float ldf(const void* p, int i, bool F32){
    return F32 ? ((const float*)p)[i] : bf2f(((const u16*)p)[i]);
}
// combined DConv weight: w[0][k][c] + w[1][k][c], layout [2][48][32]
static __device__ __forceinline__ float wsum(const void* wp, int k, int c, bool F32){
    int i0 = k*HID + c;
    return ldf(wp, i0, F32) + ldf(wp, XH*HID + i0, F32);
}
// stage tile: [16 rows][64 bf16 cols] = 128 B rows; XOR swizzle (T2/G4) so
// A-fragment ds_read_b128 at stride-128 rows doesn't pile on 4 banks.
static __device__ __forceinline__ char* stgp(char* base, int row, int off){
    return base + row*128 + (off ^ ((row & 7) << 4));
}

__global__ __launch_bounds__(256)
void rgcn_kernel(const void* __restrict__ xp_,   // [N,16]
                 const void* __restrict__ hp_,   // [N,32]
                 const void* __restrict__ wz_, const void* __restrict__ bz_,
                 const void* __restrict__ wr_, const void* __restrict__ br_,
                 const void* __restrict__ wh_, const void* __restrict__ bh_,
                 const void* __restrict__ wl_, const void* __restrict__ bl_,
                 void* __restrict__ dout_)       // out [N,8] ++ h_new [N,32]
{
    __shared__ u16   sStage[4][16*64];   // per-wave bf16 [x|h]->[x|hr]->relu(hn) tile
    __shared__ float sHf[4][16*36];      // per-wave f32 h (row pad 36 vs bank aliasing)
    __shared__ float sOut[4][16*8];      // per-wave f32 out staging
    __shared__ int sF32;

    const int tid = threadIdx.x;

    // ---- dtype detection (same scheme as previous kernel)
    if (tid == 0) {
        const u32* xw = (const u32*)xp_;
        int f = 0;
        for (int q = 0; q < 128; q++) {
            float lo = bflo(xw[q]);
            if (!(fabsf(lo) <= 1e6f)) { f = 1; break; }
        }
        sF32 = f;
    }
    __syncthreads();
    const bool F32 = (sF32 != 0);

    const int lane = tid & 63, wv = tid >> 6;
    const int c16 = lane & 15, g = lane >> 4;     // MFMA frag coords
    const int row4 = lane >> 2, q4 = lane & 3;    // staging coords
    char*  stage = (char*)sStage[wv];
    float* hf    = sHf[wv];
    float* obuf  = sOut[wv];

    // zero K-pad (stage cols 48..63) once; tile loop only writes cols 0..47
    {
        uint2 z2; z2.x = 0u; z2.y = 0u;
        *(uint2*)stgp(stage, row4, 96 + q4*8) = z2;
    }

    // ---- biases (per-lane, once)
    float bzv[2], brv[2], bhv[2];
#pragma unroll
    for (int tt = 0; tt < 2; tt++) {
        bzv[tt] = ldf(bz_, c16 + 16*tt, F32);
        brv[tt] = ldf(br_, c16 + 16*tt, F32);
        bhv[tt] = ldf(bh_, c16 + 16*tt, F32);
    }
    float blv = (c16 < OUT_DIM) ? ldf(bl_, c16, F32) : 0.f;

    // ---- B-fragments (once per wave; reused for every node tile)
    // B layout (16x16x32): col = lane&15, k = (lane>>4)*8 + e
    bf16x8 Bz[2][2], Br[2][2], Bh[2][2], Bl;
#pragma unroll
    for (int kt = 0; kt < 2; kt++) {
#pragma unroll
        for (int tt = 0; tt < 2; tt++) {
            union { u16 us[8]; bf16x8 v; } uz, ur, uh;
#pragma unroll
            for (int e = 0; e < 8; e++) {
                int k = kt*32 + g*8 + e;
                int c = c16 + 16*tt;
                float vz = 0.f, vr = 0.f, vh = 0.f;
                if (k < XH) {
                    vz = wsum(wz_, k, c, F32);
                    vr = wsum(wr_, k, c, F32);
                    vh = wsum(wh_, k, c, F32);
                }
                uz.us[e] = f2bf(vz); ur.us[e] = f2bf(vr); uh.us[e] = f2bf(vh);
            }
            Bz[kt][tt] = uz.v; Br[kt][tt] = ur.v; Bh[kt][tt] = uh.v;
        }
    }
    {
        union { u16 us[8]; bf16x8 v; } ul;
#pragma unroll
        for (int e = 0; e < 8; e++) {
            int k = g*8 + e;   // < 32 always
            float v = (c16 < OUT_DIM) ? ldf(wl_, k*OUT_DIM + c16, F32) : 0.f;
            ul.us[e] = f2bf(v);
        }
        Bl = ul.v;
    }

    const int wid = blockIdx.x*4 + wv;
    const int nw  = gridDim.x*4;

    for (int t = wid; t < NTILES; t += nw) {
        const size_t nb = (size_t)t * 16;

        // ---- stage x,h: coalesced global loads -> bf16 stage (+ f32 h copy)
        if (F32) {
            const float* xb = (const float*)xp_ + nb*IN_DIM;
            float4 xv = *(const float4*)(xb + row4*IN_DIM + q4*4);
            uint2 xp2; xp2.x = pk2(xv.x, xv.y); xp2.y = pk2(xv.z, xv.w);
            *(uint2*)stgp(stage, row4, q4*8) = xp2;
            const float* hb = (const float*)hp_ + nb*HID;
            float4 h0 = *(const float4*)(hb + row4*HID + q4*8);
            float4 h1 = *(const float4*)(hb + row4*HID + q4*8 + 4);
            uint4 hp4; hp4.x = pk2(h0.x,h0.y); hp4.y = pk2(h0.z,h0.w);
            hp4.z = pk2(h1.x,h1.y); hp4.w = pk2(h1.z,h1.w);
            *(uint4*)stgp(stage, row4, 32 + q4*16) = hp4;
            *(float4*)(hf + row4*36 + q4*8)     = h0;
            *(float4*)(hf + row4*36 + q4*8 + 4) = h1;
        } else {
            const u16* xb = (const u16*)xp_ + nb*IN_DIM;
            uint2 xv = *(const uint2*)(xb + row4*IN_DIM + q4*4);
            *(uint2*)stgp(stage, row4, q4*8) = xv;
            const u16* hb = (const u16*)hp_ + nb*HID;
            uint4 hv = *(const uint4*)(hb + row4*HID + q4*8);
            *(uint4*)stgp(stage, row4, 32 + q4*16) = hv;
            float4 e0, e1;
            e0.x = bflo(hv.x); e0.y = bfhi(hv.x); e0.z = bflo(hv.y); e0.w = bfhi(hv.y);
            e1.x = bflo(hv.z); e1.y = bfhi(hv.z); e1.z = bflo(hv.w); e1.w = bfhi(hv.w);
            *(float4*)(hf + row4*36 + q4*8)     = e0;
            *(float4*)(hf + row4*36 + q4*8 + 4) = e1;
        }
        LFENCE();

        // ---- A1 = [x | h] fragments (A: row = lane&15, k = (lane>>4)*8+e)
        bf16x8 a0 = *(const bf16x8*)stgp(stage, c16, g*16);
        bf16x8 a1 = *(const bf16x8*)stgp(stage, c16, 64 + g*16);

        // ---- GEMM1: z (cols 0..31) and r (cols 0..31), bias-seeded acc
        f32x4 accZ[2], accR[2];
#pragma unroll
        for (int tt = 0; tt < 2; tt++) {
            f32x4 az; az[0]=bzv[tt]; az[1]=bzv[tt]; az[2]=bzv[tt]; az[3]=bzv[tt];
            az = MFMA16(a0, Bz[0][tt], az);
            az = MFMA16(a1, Bz[1][tt], az);
            accZ[tt] = az;
            f32x4 ar; ar[0]=brv[tt]; ar[1]=brv[tt]; ar[2]=brv[tt]; ar[3]=brv[tt];
            ar = MFMA16(a0, Br[0][tt], ar);
            ar = MFMA16(a1, Br[1][tt], ar);
            accR[tt] = ar;
        }

        // ---- glue 1: z = sig, r = sig, write hr = h*r over stage h-half
        // C layout: col = lane&15 (+16*tt), row = g*4 + rr
        float hvv[2][4], zz[2][4];
#pragma unroll
        for (int tt = 0; tt < 2; tt++) {
#pragma unroll
            for (int rr = 0; rr < 4; rr++) {
                int nl = g*4 + rr;
                float hcur = hf[nl*36 + c16 + 16*tt];
                hvv[tt][rr] = hcur;
                zz[tt][rr]  = sigm(accZ[tt][rr]);
                float rv    = sigm(accR[tt][rr]);
                *(u16*)stgp(stage, nl, 32 + 2*c16 + 32*tt) = f2bf(hcur * rv);
            }
        }
        LFENCE();

        // ---- GEMMh: A2 = [x | h*r] (x half still valid in stage)
        bf16x8 b0 = *(const bf16x8*)stgp(stage, c16, g*16);
        bf16x8 b1 = *(const bf16x8*)stgp(stage, c16, 64 + g*16);
        f32x4 accH[2];
#pragma unroll
        for (int tt = 0; tt < 2; tt++) {
            f32x4 ah; ah[0]=bhv[tt]; ah[1]=bhv[tt]; ah[2]=bhv[tt]; ah[3]=bhv[tt];
            ah = MFMA16(b0, Bh[0][tt], ah);
            ah = MFMA16(b1, Bh[1][tt], ah);
            accH[tt] = ah;
        }

        // ---- glue 2: h_new = z*h + (1-z)*tanh; stage relu(h_new) for GEMMout
        // (z and h~ fragments have identical (row,col) layout -> no shuffle)
#pragma unroll
        for (int tt = 0; tt < 2; tt++) {
#pragma unroll
            for (int rr = 0; rr < 4; rr++) {
                int nl = g*4 + rr;
                float ht = tanh_(accH[tt][rr]);
                float z  = zz[tt][rr];
                float hn = z*hvv[tt][rr] + (1.f - z)*ht;
                hf[nl*36 + c16 + 16*tt] = hn;                      // overwrite h (consumed)
                *(u16*)stgp(stage, nl, 2*c16 + 32*tt) = f2bf(fmaxf(hn, 0.f));
            }
        }
        LFENCE();

        // ---- GEMMout: [16,32] @ [32,8] (cols 8..15 padded)
        bf16x8 a3 = *(const bf16x8*)stgp(stage, c16, g*16);
        f32x4 accO; accO[0]=blv; accO[1]=blv; accO[2]=blv; accO[3]=blv;
        accO = MFMA16(a3, Bl, accO);
        if (c16 < OUT_DIM) {
#pragma unroll
            for (int rr = 0; rr < 4; rr++) obuf[(g*4+rr)*OUT_DIM + c16] = accO[rr];
        }
        LFENCE();

        // ---- coalesced stores via LDS staging
        if (F32) {
            float* outp = (float*)dout_;
            float* hnp  = outp + (size_t)N_NODES*OUT_DIM;
            float4 s0 = *(const float4*)(hf + row4*36 + q4*8);
            float4 s1 = *(const float4*)(hf + row4*36 + q4*8 + 4);
            float* hd = hnp + (nb + row4)*HID + q4*8;
            *(float4*)hd = s0; *(float4*)(hd+4) = s1;
            if (lane < 32) {
                float4 o = *(const float4*)(obuf + (lane>>1)*OUT_DIM + (lane&1)*4);
                *(float4*)(outp + (nb + (lane>>1))*OUT_DIM + (lane&1)*4) = o;
            }
        } else {
            u16* outp = (u16*)dout_;
            u16* hnp  = outp + (size_t)N_NODES*OUT_DIM;
            float4 s0 = *(const float4*)(hf + row4*36 + q4*8);
            float4 s1 = *(const float4*)(hf + row4*36 + q4*8 + 4);
            uint4 pv; pv.x = pk2(s0.x,s0.y); pv.y = pk2(s0.z,s0.w);
            pv.z = pk2(s1.x,s1.y); pv.w = pk2(s1.z,s1.w);
            *(uint4*)(hnp + (nb + row4)*HID + q4*8) = pv;
            if (lane < 16) {
                float4 o0 = *(const float4*)(obuf + lane*OUT_DIM);
                float4 o1 = *(const float4*)(obuf + lane*OUT_DIM + 4);
                uint4 ov; ov.x = pk2(o0.x,o0.y); ov.y = pk2(o0.z,o0.w);
                ov.z = pk2(o1.x,o1.y); ov.w = pk2(o1.z,o1.w);
                *(uint4*)(outp + (nb + lane)*OUT_DIM) = ov;
            }
        }
    }
}

extern "C" void kernel_launch(void* const* d_in, const int* in_sizes, int n_in,
                              void* d_out, int out_size, void* d_ws, size_t ws_size,
                              hipStream_t stream) {
    // setup_inputs() order:
    // 0 x, 1 edge_index(unused), 2 edge_weight(unused), 3 h,
    // 4 w_z, 5 b_z, 6 w_r, 7 b_r, 8 w_h, 9 b_h, 10 w_lin, 11 b_lin
    const int block = 256;     // 4 waves; each wave owns independent 16-node tiles
    const int grid  = 2048;    // 8192 waves, grid-stride over 31250 tiles
    rgcn_kernel<<<grid, block, 0, stream>>>(
        d_in[0], d_in[3], d_in[4], d_in[5], d_in[6], d_in[7],
        d_in[8], d_in[9], d_in[10], d_in[11], d_out);
}